// Round 5
// baseline (287.346 us; speedup 1.0000x reference)
//
#include <hip/hip_runtime.h>

// GRU autoregressive decoder, bf16-MFMA persistent-weight, 4-wave blocks.
// B=16384, I=32, H=128, 30 steps, x0 = x[:,30,:], y feeds back as x.
//
// Round 8 -> 9 changes (shrink the barrier domain):
//  * 4-wave blocks (256 thr), each wave owns 32 hidden units (2 col-tiles).
//    Grid 512 x 256thr -> TWO independent blocks per CU, each with its own
//    4-wave barrier. R8 showed 8-wave blocks never overlap (VALUBusy flat
//    44% regardless of grid): the workgroup-wide barrier lockstepped the CU.
//    Two decoupled recurrences/CU fill each other's latency stalls.
//  * Persistent weights double per wave: {r,z,ni,nh} x 2ct x 4kt = 128 VGPR.
//    __launch_bounds__(256,2) -> 256-reg cap under BOTH possible semantics
//    (2 waves/EU == 2 blocks/CU for 4-wave blocks) -- the R5/R7 ambiguity
//    becomes moot. Budget ~210 regs: fits, no spill.
//  * A-fragments now feed 2 col-tiles (32 MFMA per 4 ds_read_b128): 2x the
//    MFMA:LDS-read ratio of R8.
//  * exp2-form activations: fold_kernel pre-scales W*/b* by -log2e (r,z) and
//    +2log2e (n-gates; Whh_n/bhh_n scaled at load). sigm = rcp(1+exp2(a')),
//    tanh = 1-2*rcp(1+exp2(t')) -- kills the per-element *log2e multiplies
//    (3 per elem x 63M elems).
//  * Keeps: folded recurrence (x-GEMM folded into K=128 Wstar), ONE LDS-only
//    barrier per step, Wout frags in LDS, HBS=144, rcp activations.

#define NB    16384
#define TT    60
#define II    32
#define HH    128
#define NSTEP 30
#define SEQ0  30
#define BM    32
#define HBS   144   // bf16 h-row stride: 288B rows
#define XBS   40    // bf16 x-row stride (step-0 x0 only)

// d_ws layout (floats): Wstar[384][128] at 0, bstar[384] at 49152.
// NOTE: fold_kernel stores these PRE-SCALED: r,z rows by -log2e, ni rows by
// +2log2e (exp2-form activations).
#define WS_WSTAR 0
#define WS_BSTAR (384 * 128)

#define S_RZ (-1.4426950408889634f)   // -log2(e)
#define S_N  ( 2.8853900817779268f)   // +2*log2(e)

typedef __attribute__((ext_vector_type(8))) short bf16x8;
typedef __attribute__((ext_vector_type(4))) float f32x4;

#define MFMA(a, b, c) __builtin_amdgcn_mfma_f32_16x16x32_bf16((a), (b), (c), 0, 0, 0)

// LDS-only barrier: wait DS ops, sync, pin scheduler (guide rule #18).
#define LDS_BARRIER() do {                                          \
    asm volatile("s_waitcnt lgkmcnt(0)\n\ts_barrier" ::: "memory"); \
    __builtin_amdgcn_sched_barrier(0);                              \
} while (0)

#if __has_builtin(__builtin_amdgcn_exp2f)
#define EXP2(x) __builtin_amdgcn_exp2f(x)
#else
#define EXP2(x) exp2f(x)
#endif
#define RCP(x) __builtin_amdgcn_rcpf(x)

__device__ __forceinline__ short f2bf(float x) {  // RNE fp32->bf16
    unsigned u = __float_as_uint(x);
    u += 0x7FFFu + ((u >> 16) & 1u);
    return (short)(u >> 16);
}
__device__ __forceinline__ bf16x8 ldw8(const float* p) {  // 8 fp32 -> bf16x8
    float4 a = *(const float4*)p;
    float4 b = *(const float4*)(p + 4);
    bf16x8 f;
    f[0] = f2bf(a.x); f[1] = f2bf(a.y); f[2] = f2bf(a.z); f[3] = f2bf(a.w);
    f[4] = f2bf(b.x); f[5] = f2bf(b.y); f[6] = f2bf(b.z); f[7] = f2bf(b.w);
    return f;
}
__device__ __forceinline__ bf16x8 ldw8s(const float* p, float s) {  // scaled
    float4 a = *(const float4*)p;
    float4 b = *(const float4*)(p + 4);
    bf16x8 f;
    f[0] = f2bf(a.x * s); f[1] = f2bf(a.y * s); f[2] = f2bf(a.z * s); f[3] = f2bf(a.w * s);
    f[4] = f2bf(b.x * s); f[5] = f2bf(b.y * s); f[6] = f2bf(b.z * s); f[7] = f2bf(b.w * s);
    return f;
}
// ap = -log2e * a  ->  sigmoid(a) = rcp(1 + 2^ap)
__device__ __forceinline__ float sigm2(float ap) {
    return RCP(1.0f + EXP2(ap));
}
// tp = 2*log2e * t ->  tanh(t) = 1 - 2*rcp(1 + 2^tp)
__device__ __forceinline__ float tanh2(float tp) {
    return fmaf(-2.0f, RCP(1.0f + EXP2(tp)), 1.0f);
}

// ---- prep: folded weights, PRE-SCALED for exp2-form activations ----
// Wstar[jg][k] = scale * [ (gate<2 ? Whh[jg][k] : 0) + sum_i Wih[jg][i]*Wout[i][k] ]
// bstar[jg]    = scale * [ bih[jg] + (gate<2 ? bhh[jg] : 0) + sum_i Wih[jg][i]*bout[i] ]
__global__ void fold_kernel(const float* __restrict__ Wih,
                            const float* __restrict__ Whh,
                            const float* __restrict__ bih,
                            const float* __restrict__ bhh,
                            const float* __restrict__ Wout,
                            const float* __restrict__ bout,
                            float* __restrict__ ws)
{
    const int jg = blockIdx.x;     // 0..383 = gate*128 + j
    const int k  = threadIdx.x;    // 0..127
    const int gate = jg >> 7;
    const float sc = (gate < 2) ? S_RZ : S_N;
    float acc  = (gate < 2) ? Whh[(size_t)jg * HH + k] : 0.0f;
    float bacc = 0.0f;
    #pragma unroll 8
    for (int i = 0; i < II; ++i) {
        const float w = Wih[(size_t)jg * II + i];
        acc  += w * Wout[(size_t)i * HH + k];
        bacc += w * bout[i];
    }
    ws[WS_WSTAR + (size_t)jg * HH + k] = acc * sc;
    if (k == 0)
        ws[WS_BSTAR + jg] = (bih[jg] + ((gate < 2) ? bhh[jg] : 0.0f) + bacc) * sc;
}

__global__ __launch_bounds__(256, 2)
void gru_mfma_kernel(const float* __restrict__ x,
                     const float* __restrict__ h0,
                     const float* __restrict__ Wih,
                     const float* __restrict__ Whh,
                     const float* __restrict__ bih,
                     const float* __restrict__ bhh,
                     const float* __restrict__ Wout,
                     const float* __restrict__ bout,
                     const float* __restrict__ ws,
                     float* __restrict__ out)
{
    __shared__ short shb[2][BM * HBS];  // bf16 h, double-buffered (18.4 KB)
    __shared__ short sxb[BM * XBS];     // bf16 x0 (step 0 only, 2.5 KB)
    __shared__ short sWo[2 * 4 * 64 * 8];  // Wout B-frags (8 KB), unscaled

    const int tid    = threadIdx.x;
    const int lane   = tid & 63;
    const int wave   = __builtin_amdgcn_readfirstlane(tid >> 6);  // 0..3
    const int n16    = lane & 15;   // MFMA col / A-row index
    const int quad   = lane >> 4;   // MFMA k-group / D-row group
    const int rowblk = blockIdx.x * BM;

    // ---- persistent n-gate h-weights, scaled by 2log2e: wave owns units
    //      [32w, 32w+32) as 2 col-tiles ----
    bf16x8 Bnh[2][4];
    float  b_nh[2];
    #pragma unroll
    for (int ct = 0; ct < 2; ++ct) {
        const int jc = wave * 32 + ct * 16 + n16;
        const float* wn = Whh + (size_t)(2 * HH + jc) * HH;
        #pragma unroll
        for (int kt = 0; kt < 4; ++kt)
            Bnh[ct][kt] = ldw8s(wn + kt * 32 + quad * 8, S_N);
        b_nh[ct] = bhh[2 * HH + jc] * S_N;
    }
    // ---- phase-2 tile assignment; Wout frags staged to LDS by waves 0-1 ----
    const int mt2 = wave >> 1;        // 0/1: which 16 rows of the 32
    const int ct2 = wave & 1;         // 0/1: which 16 output cols
    if (wave < 2) {                   // wave w stages coltile=w's fragments
        #pragma unroll
        for (int kt = 0; kt < 4; ++kt) {
            bf16x8 t = ldw8(Wout + (size_t)(wave * 16 + n16) * HH + kt * 32 + quad * 8);
            *(bf16x8*)&sWo[((wave * 4 + kt) * 64 + lane) * 8] = t;
        }
    }
    const float b_o = bout[ct2 * 16 + n16];

    // ---- lane-private fp32 h-state: hst[mt][ct][reg] = h[row][col],
    //      row = mt*16 + quad*4 + reg, col = wave*32 + ct*16 + n16 ----
    float hst[2][2][4];
    #pragma unroll
    for (int mt = 0; mt < 2; ++mt)
        #pragma unroll
        for (int ct = 0; ct < 2; ++ct)
            #pragma unroll
            for (int reg = 0; reg < 4; ++reg)
                hst[mt][ct][reg] =
                    h0[(size_t)(rowblk + mt * 16 + quad * 4 + reg) * HH + wave * 32 + ct * 16 + n16];

    // ---- stage bf16 h0 and x0 into LDS (one-time, cooperative) ----
    {
        const int r  = tid >> 3;            // 32 rows, 8 threads/row
        const int c0 = (tid & 7) * 16;      // 16 cols each
        const float* src = h0 + (size_t)(rowblk + r) * HH + c0;
        *(bf16x8*)&shb[0][r * HBS + c0]     = ldw8(src);
        *(bf16x8*)&shb[0][r * HBS + c0 + 8] = ldw8(src + 8);
    }
    if (tid < 128) {
        const int r  = tid >> 2;            // 32 rows, 4 threads/row
        const int c0 = (tid & 3) * 8;
        *(bf16x8*)&sxb[r * XBS + c0] = ldw8(x + ((size_t)(rowblk + r) * TT + SEQ0) * II + c0);
    }
    __syncthreads();

    // ================= peeled step 0: un-folded (scaled) weights + x0 =====
    #pragma unroll
    for (int ct = 0; ct < 2; ++ct) {       // ct outer: transient weights tight
        const int jc = wave * 32 + ct * 16 + n16;
        bf16x8 Br0[4], Bz0[4];
        const float* wr = Whh + (size_t)jc * HH;
        const float* wz = Whh + (size_t)(HH + jc) * HH;
        #pragma unroll
        for (int kt = 0; kt < 4; ++kt) {
            Br0[kt] = ldw8s(wr + kt * 32 + quad * 8, S_RZ);
            Bz0[kt] = ldw8s(wz + kt * 32 + quad * 8, S_RZ);
        }
        bf16x8 Bxr = ldw8s(Wih + (size_t)jc * II + quad * 8, S_RZ);
        bf16x8 Bxz = ldw8s(Wih + (size_t)(HH + jc) * II + quad * 8, S_RZ);
        bf16x8 Bxn = ldw8s(Wih + (size_t)(2 * HH + jc) * II + quad * 8, S_N);
        const float b_r0 = (bih[jc] + bhh[jc]) * S_RZ;
        const float b_z0 = (bih[HH + jc] + bhh[HH + jc]) * S_RZ;
        const float b_n0 = bih[2 * HH + jc] * S_N;

        #pragma unroll
        for (int mt = 0; mt < 2; ++mt) {
            f32x4 ar  = (f32x4){b_r0, b_r0, b_r0, b_r0};
            f32x4 az  = (f32x4){b_z0, b_z0, b_z0, b_z0};
            f32x4 anh = (f32x4){b_nh[ct], b_nh[ct], b_nh[ct], b_nh[ct]};
            f32x4 anx = (f32x4){b_n0, b_n0, b_n0, b_n0};
            #pragma unroll
            for (int kt = 0; kt < 4; ++kt) {
                bf16x8 A = *(const bf16x8*)&shb[0][(mt * 16 + n16) * HBS + kt * 32 + quad * 8];
                ar  = MFMA(A, Br0[kt], ar);
                az  = MFMA(A, Bz0[kt], az);
                anh = MFMA(A, Bnh[ct][kt], anh);
            }
            {
                bf16x8 Ax = *(const bf16x8*)&sxb[(mt * 16 + n16) * XBS + quad * 8];
                ar  = MFMA(Ax, Bxr, ar);
                az  = MFMA(Ax, Bxz, az);
                anx = MFMA(Ax, Bxn, anx);
            }
            #pragma unroll
            for (int reg = 0; reg < 4; ++reg) {
                const float r = sigm2(ar[reg]);
                const float z = sigm2(az[reg]);
                const float n = tanh2(anx[reg] + r * anh[reg]);
                const float hnew = n + z * (hst[mt][ct][reg] - n);
                hst[mt][ct][reg] = hnew;
                shb[1][(mt * 16 + quad * 4 + reg) * HBS + wave * 32 + ct * 16 + n16] = f2bf(hnew);
            }
        }
    }

    // ---- folded steady-state weights (pre-scaled in ws by fold_kernel) ----
    bf16x8 Brs[2][4], Bzs[2][4], Bni[2][4];
    float  b_rs[2], b_zs[2], b_ni[2];
    #pragma unroll
    for (int ct = 0; ct < 2; ++ct) {
        const int jc = wave * 32 + ct * 16 + n16;
        const float* pr = ws + WS_WSTAR + (size_t)jc * HH;
        const float* pz = ws + WS_WSTAR + (size_t)(HH + jc) * HH;
        const float* pn = ws + WS_WSTAR + (size_t)(2 * HH + jc) * HH;
        #pragma unroll
        for (int kt = 0; kt < 4; ++kt) {
            Brs[ct][kt] = ldw8(pr + kt * 32 + quad * 8);
            Bzs[ct][kt] = ldw8(pz + kt * 32 + quad * 8);
            Bni[ct][kt] = ldw8(pn + kt * 32 + quad * 8);
        }
        b_rs[ct] = ws[WS_BSTAR + jc];
        b_zs[ct] = ws[WS_BSTAR + HH + jc];
        b_ni[ct] = ws[WS_BSTAR + 2 * HH + jc];
    }

    __syncthreads();   // step-0 h' (and sWo) visible to all 4 waves

    // ================= steps 0..29: {phase2(s) || phase1(s+1)} =============
    // Loop-top invariant: barrier passed; shb[q] holds h_{s+1}. Phase 2 reads
    // shb[q]; phase 1 of step s+1 reads shb[q], writes shb[p] — disjoint, so
    // ONE (LDS-only, 4-wave) barrier per step.
    int p = 0;
    for (int s = 0; s < NSTEP; ++s) {
        const int q = 1 - p;

        // ---- phase 2 of step s: y = h_{s+1} @ Wout^T + bout (all 4 waves) --
        {
            f32x4 yo = (f32x4){b_o, b_o, b_o, b_o};
            #pragma unroll
            for (int kt = 0; kt < 4; ++kt) {
                bf16x8 A2  = *(const bf16x8*)&shb[q][(mt2 * 16 + n16) * HBS + kt * 32 + quad * 8];
                bf16x8 Bof = *(const bf16x8*)&sWo[((ct2 * 4 + kt) * 64 + lane) * 8];
                yo = MFMA(A2, Bof, yo);
            }
            #pragma unroll
            for (int reg = 0; reg < 4; ++reg) {
                const int r_l = mt2 * 16 + quad * 4 + reg;
                out[(size_t)(rowblk + r_l) * (NSTEP * II) + s * II + ct2 * 16 + n16] = yo[reg];
            }
        }

        if (s == NSTEP - 1) break;   // last y written; no more recurrence

        // ---- phase 1 of step s+1: gates + h update (folded, K=128) ----
        #pragma unroll
        for (int mt = 0; mt < 2; ++mt) {
            bf16x8 A[4];
            #pragma unroll
            for (int kt = 0; kt < 4; ++kt)
                A[kt] = *(const bf16x8*)&shb[q][(mt * 16 + n16) * HBS + kt * 32 + quad * 8];

            #pragma unroll
            for (int ct = 0; ct < 2; ++ct) {     // A reused across both ct
                f32x4 ar  = (f32x4){b_rs[ct], b_rs[ct], b_rs[ct], b_rs[ct]};
                f32x4 az  = (f32x4){b_zs[ct], b_zs[ct], b_zs[ct], b_zs[ct]};
                f32x4 anh = (f32x4){b_nh[ct], b_nh[ct], b_nh[ct], b_nh[ct]};
                f32x4 ani = (f32x4){b_ni[ct], b_ni[ct], b_ni[ct], b_ni[ct]};
                #pragma unroll
                for (int kt = 0; kt < 4; ++kt) { // 4 indep acc chains
                    ar  = MFMA(A[kt], Brs[ct][kt], ar);
                    az  = MFMA(A[kt], Bzs[ct][kt], az);
                    anh = MFMA(A[kt], Bnh[ct][kt], anh);
                    ani = MFMA(A[kt], Bni[ct][kt], ani);
                }
                #pragma unroll
                for (int reg = 0; reg < 4; ++reg) {
                    const float r = sigm2(ar[reg]);
                    const float z = sigm2(az[reg]);
                    const float n = tanh2(ani[reg] + r * anh[reg]);
                    const float hnew = n + z * (hst[mt][ct][reg] - n);
                    hst[mt][ct][reg] = hnew;
                    shb[p][(mt * 16 + quad * 4 + reg) * HBS + wave * 32 + ct * 16 + n16] = f2bf(hnew);
                }
            }
        }

        p = q;             // next step reads the buffer just written
        LDS_BARRIER();     // one LDS-only 4-wave barrier per step
    }
}

extern "C" void kernel_launch(void* const* d_in, const int* in_sizes, int n_in,
                              void* d_out, int out_size, void* d_ws, size_t ws_size,
                              hipStream_t stream) {
    (void)in_sizes; (void)n_in; (void)out_size; (void)ws_size;
    const float* x    = (const float*)d_in[0];
    const float* h0   = (const float*)d_in[1];
    const float* Wih  = (const float*)d_in[2];
    const float* Whh  = (const float*)d_in[3];
    const float* bih  = (const float*)d_in[4];
    const float* bhh  = (const float*)d_in[5];
    const float* Wout = (const float*)d_in[6];
    const float* bout = (const float*)d_in[7];
    float* out = (float*)d_out;
    float* ws  = (float*)d_ws;

    fold_kernel<<<dim3(384), dim3(128), 0, stream>>>(Wih, Whh, bih, bhh,
                                                     Wout, bout, ws);
    dim3 grid(NB / BM);   // 512 blocks x 256 thr -> 2 independent blocks/CU
    dim3 block(256);
    gru_mfma_kernel<<<grid, block, 0, stream>>>(x, h0, Wih, Whh, bih, bhh,
                                                Wout, bout, ws, out);
}

// Round 7
// 256.791 us; speedup vs baseline: 1.1190x; 1.1190x over previous
//
#include <hip/hip_runtime.h>

// GRU autoregressive decoder, bf16-MFMA persistent-weight, 8-wave blocks.
// B=16384, I=32, H=128, 30 steps, x0 = x[:,30,:], y feeds back as x.
//
// Round 10 -> 11: FIX the swizzled h'-write column. R10 built the write
// offset from 2*n16; the true column is the lane's global hidden unit
// j = wave*16 + n16. All 8 waves were writing the same 16 columns; cols
// 16-127 of the next-step buffer stayed uninitialized -> absmax 1.8e33.
// One-line fix; design otherwise identical to R10:
//  * VALU-content attack (vs R6 base 106us): exp2-prescaled activations
//    (fold pre-scales W*/b* by -log2e / +2log2e), v_cvt_pk_bf16_f32 packs
//    the h' bf16 store pairs, step loop unrolled x2 with literal buffer
//    index, pow2 256B rows, all in-loop LDS addrs = precomputed lane bases
//    + immediates, out ptrs strength-reduced. Zero in-loop address VALU.
//  * XOR-swizzle shb: elem (r,c) at byte r*256 + ((2c) ^ ((r&15)<<4)).
//    h' b16 writes drop 8-way -> <=4-way; b128 reads spread 2-way (free).
//  * __launch_bounds__(512,1): grid=256 -> 1 block/CU anyway; 256-reg cap,
//    no spill at ~150 live regs (R7/R9 lesson: spill costs more than occ).
//  * Keeps: folded recurrence (x-GEMM folded into K=128 Wstar/bstar in
//    d_ws), ONE LDS-only barrier per step, peeled step 0 with real x0.

#define NB    16384
#define TT    60
#define II    32
#define HH    128
#define NSTEP 30
#define SEQ0  30
#define BM    64
#define XBS   40            // bf16 x-row stride (step-0 x0 only)
#define ROWB  256           // shb row bytes (128 bf16, pow2)
#define BUFB  (BM * ROWB)   // 16384 B per h buffer

// d_ws layout (floats): Wstar[384][128] at 0, bstar[384] at 49152.
// PRE-SCALED: r,z rows by -log2e, ni rows by +2log2e (exp2-form activations).
#define WS_WSTAR 0
#define WS_BSTAR (384 * 128)

#define S_RZ (-1.4426950408889634f)   // -log2(e)
#define S_N  ( 2.8853900817779268f)   // +2*log2(e)

typedef __attribute__((ext_vector_type(8))) short bf16x8;
typedef __attribute__((ext_vector_type(4))) float f32x4;

#define MFMA(a, b, c) __builtin_amdgcn_mfma_f32_16x16x32_bf16((a), (b), (c), 0, 0, 0)

// LDS-only barrier: wait DS ops, sync, pin scheduler (guide rule #18).
#define LDS_BARRIER() do {                                          \
    asm volatile("s_waitcnt lgkmcnt(0)\n\ts_barrier" ::: "memory"); \
    __builtin_amdgcn_sched_barrier(0);                              \
} while (0)

#define EXP2(x) __builtin_amdgcn_exp2f(x)
#define RCP(x)  __builtin_amdgcn_rcpf(x)

__device__ __forceinline__ short f2bf(float x) {  // RNE fp32->bf16 (init paths)
    unsigned u = __float_as_uint(x);
    u += 0x7FFFu + ((u >> 16) & 1u);
    return (short)(u >> 16);
}
__device__ __forceinline__ unsigned cvt_pk_bf16(float lo, float hi) {
    unsigned r;  // D[15:0]=bf16(S0) RNE, D[31:16]=bf16(S1)
    asm("v_cvt_pk_bf16_f32 %0, %1, %2" : "=v"(r) : "v"(lo), "v"(hi));
    return r;
}
__device__ __forceinline__ bf16x8 ldw8(const float* p) {  // 8 fp32 -> bf16x8
    float4 a = *(const float4*)p;
    float4 b = *(const float4*)(p + 4);
    bf16x8 f;
    f[0] = f2bf(a.x); f[1] = f2bf(a.y); f[2] = f2bf(a.z); f[3] = f2bf(a.w);
    f[4] = f2bf(b.x); f[5] = f2bf(b.y); f[6] = f2bf(b.z); f[7] = f2bf(b.w);
    return f;
}
__device__ __forceinline__ bf16x8 ldw8s(const float* p, float s) {  // scaled
    float4 a = *(const float4*)p;
    float4 b = *(const float4*)(p + 4);
    bf16x8 f;
    f[0] = f2bf(a.x * s); f[1] = f2bf(a.y * s); f[2] = f2bf(a.z * s); f[3] = f2bf(a.w * s);
    f[4] = f2bf(b.x * s); f[5] = f2bf(b.y * s); f[6] = f2bf(b.z * s); f[7] = f2bf(b.w * s);
    return f;
}
// ap = -log2e * a  ->  sigmoid(a) = rcp(1 + 2^ap)
__device__ __forceinline__ float sigm2(float ap) { return RCP(1.0f + EXP2(ap)); }
// tp = 2*log2e * t ->  tanh(t) = 1 - 2*rcp(1 + 2^tp)
__device__ __forceinline__ float tanh2(float tp) {
    return fmaf(-2.0f, RCP(1.0f + EXP2(tp)), 1.0f);
}

// ---- prep: folded weights, PRE-SCALED for exp2-form activations ----
__global__ void fold_kernel(const float* __restrict__ Wih,
                            const float* __restrict__ Whh,
                            const float* __restrict__ bih,
                            const float* __restrict__ bhh,
                            const float* __restrict__ Wout,
                            const float* __restrict__ bout,
                            float* __restrict__ ws)
{
    const int jg = blockIdx.x;     // 0..383 = gate*128 + j
    const int k  = threadIdx.x;    // 0..127
    const int gate = jg >> 7;
    const float sc = (gate < 2) ? S_RZ : S_N;
    float acc  = (gate < 2) ? Whh[(size_t)jg * HH + k] : 0.0f;
    float bacc = 0.0f;
    #pragma unroll 8
    for (int i = 0; i < II; ++i) {
        const float w = Wih[(size_t)jg * II + i];
        acc  += w * Wout[(size_t)i * HH + k];
        bacc += w * bout[i];
    }
    ws[WS_WSTAR + (size_t)jg * HH + k] = acc * sc;
    if (k == 0)
        ws[WS_BSTAR + jg] = (bih[jg] + ((gate < 2) ? bhh[jg] : 0.0f) + bacc) * sc;
}

__global__ __launch_bounds__(512, 1)
void gru_mfma_kernel(const float* __restrict__ x,
                     const float* __restrict__ h0,
                     const float* __restrict__ Wih,
                     const float* __restrict__ Whh,
                     const float* __restrict__ bih,
                     const float* __restrict__ bhh,
                     const float* __restrict__ Wout,
                     const float* __restrict__ bout,
                     const float* __restrict__ ws,
                     float* __restrict__ out)
{
    __shared__ short shb[2][BM * 128];  // bf16 h, double-buffered, 32 KB,
                                        // XOR-swizzled: elem (r,c) at byte
                                        // r*256 + ((2c) ^ ((r&15)<<4))
    __shared__ short sxb[BM * XBS];     // bf16 x0 (step 0 only, 5.1 KB)
    char* shbb = (char*)shb;

    const int tid    = threadIdx.x;
    const int lane   = tid & 63;
    const int wave   = __builtin_amdgcn_readfirstlane(tid >> 6);  // 0..7
    const int n16    = lane & 15;   // MFMA col / A-row index
    const int quad   = lane >> 4;   // MFMA k-group / D-row group
    const int rowblk = blockIdx.x * BM;
    const int j      = wave * 16 + n16;   // hidden unit this lane's gate col

    // ---- swizzled LDS lane bases (prologue-only VALU) ----
    // read: element row=mt*16+n16 (row&15==n16), k-bytes kt*64+quad*16:
    //   addr = n16*256 + ((kt*64 + quad*16) ^ (n16<<4)) + mt*4096 [+buf]
    int rb[4];
    #pragma unroll
    for (int kt = 0; kt < 4; ++kt)
        rb[kt] = n16 * 256 + ((kt * 64 + quad * 16) ^ (n16 << 4));
    // write: element row=mt*16+quad*4+reg (row&15=quad*4+reg), col j:
    //   addr = quad*1024 + ((2j) ^ (quad<<6) ^ (reg<<4)) + mt*4096 + reg*256
    // (R10 bug: used 2*n16 here -> all waves hit the same 16 columns.)
    int wb[4];
    #pragma unroll
    for (int rg = 0; rg < 4; ++rg)
        wb[rg] = quad * 1024 + ((2 * j) ^ (quad << 6) ^ (rg << 4));

    // ---- persistent n-gate h-weights, scaled by 2log2e ----
    bf16x8 Bnh[4];
    float  b_nh;
    {
        const float* wn = Whh + (size_t)(2 * HH + j) * HH;
        #pragma unroll
        for (int kt = 0; kt < 4; ++kt)
            Bnh[kt] = ldw8s(wn + kt * 32 + quad * 8, S_N);
        b_nh = bhh[2 * HH + j] * S_N;
    }
    // ---- phase-2 tile assignment + this wave's Wout column-tile ----
    const int rowtile = wave >> 1;    // 0..3: which 16 rows of the 64
    const int coltile = wave & 1;     // 0/1:  which 16 output cols
    bf16x8 Bo[4];
    float  b_o;
    {
        const int i = coltile * 16 + n16;
        #pragma unroll
        for (int kt = 0; kt < 4; ++kt)
            Bo[kt] = ldw8(Wout + (size_t)i * HH + kt * 32 + quad * 8);
        b_o = bout[i];
    }

    // ---- lane-private fp32 h-state ----
    float hst[4][4];
    #pragma unroll
    for (int mt = 0; mt < 4; ++mt)
        #pragma unroll
        for (int reg = 0; reg < 4; ++reg)
            hst[mt][reg] = h0[(size_t)(rowblk + mt * 16 + quad * 4 + reg) * HH + j];

    // ---- strength-reduced out pointers: rows rowtile*16+quad*4+{0..3} ----
    float* yp0;
    float* yp1;
    {
        const int r0 = rowblk + rowtile * 16 + quad * 4;
        yp0 = out + (size_t)r0 * (NSTEP * II) + coltile * 16 + n16;
        yp1 = yp0 + 2 * (size_t)(NSTEP * II);
    }

    // ---- stage bf16 h0 (swizzled) and x0 into LDS ----
    {
        const int r  = tid >> 3;            // 64 rows, 8 threads/row
        const int cb = (tid & 7) * 32;      // byte col offset (16 cols)
        const int sw = (r & 15) << 4;
        const float* src = h0 + (size_t)(rowblk + r) * HH + (tid & 7) * 16;
        *(bf16x8*)(shbb + r * ROWB + (cb ^ sw))        = ldw8(src);
        *(bf16x8*)(shbb + r * ROWB + ((cb + 16) ^ sw)) = ldw8(src + 8);
    }
    if (tid < 256) {
        const int r  = tid >> 2;            // 64 rows, 4 threads/row
        const int c0 = (tid & 3) * 8;
        *(bf16x8*)&sxb[r * XBS + c0] = ldw8(x + ((size_t)(rowblk + r) * TT + SEQ0) * II + c0);
    }
    __syncthreads();

    // ================= peeled step 0: un-folded (scaled) weights + x0 =====
    {
        bf16x8 Br0[4], Bz0[4], Bxr, Bxz, Bxn;
        const float* wr = Whh + (size_t)j * HH;
        const float* wz = Whh + (size_t)(HH + j) * HH;
        #pragma unroll
        for (int kt = 0; kt < 4; ++kt) {
            Br0[kt] = ldw8s(wr + kt * 32 + quad * 8, S_RZ);
            Bz0[kt] = ldw8s(wz + kt * 32 + quad * 8, S_RZ);
        }
        Bxr = ldw8s(Wih + (size_t)j * II + quad * 8, S_RZ);
        Bxz = ldw8s(Wih + (size_t)(HH + j) * II + quad * 8, S_RZ);
        Bxn = ldw8s(Wih + (size_t)(2 * HH + j) * II + quad * 8, S_N);
        const float b_r0 = (bih[j] + bhh[j]) * S_RZ;
        const float b_z0 = (bih[HH + j] + bhh[HH + j]) * S_RZ;
        const float b_n0 = bih[2 * HH + j] * S_N;

        #pragma unroll
        for (int mt = 0; mt < 4; ++mt) {
            f32x4 ar  = (f32x4){b_r0, b_r0, b_r0, b_r0};
            f32x4 az  = (f32x4){b_z0, b_z0, b_z0, b_z0};
            f32x4 anh = (f32x4){b_nh, b_nh, b_nh, b_nh};
            f32x4 anx = (f32x4){b_n0, b_n0, b_n0, b_n0};
            #pragma unroll
            for (int kt = 0; kt < 4; ++kt) {
                bf16x8 A = *(const bf16x8*)(shbb + rb[kt] + mt * 4096);
                ar  = MFMA(A, Br0[kt], ar);
                az  = MFMA(A, Bz0[kt], az);
                anh = MFMA(A, Bnh[kt], anh);
            }
            {
                bf16x8 Ax = *(const bf16x8*)&sxb[(mt * 16 + n16) * XBS + quad * 8];
                ar  = MFMA(Ax, Bxr, ar);
                az  = MFMA(Ax, Bxz, az);
                anx = MFMA(Ax, Bxn, anx);
            }
            float hn[4];
            #pragma unroll
            for (int reg = 0; reg < 4; ++reg) {
                const float r = sigm2(ar[reg]);
                const float z = sigm2(az[reg]);
                const float n = tanh2(anx[reg] + r * anh[reg]);
                const float hnew = n + z * (hst[mt][reg] - n);
                hst[mt][reg] = hnew;
                hn[reg] = hnew;
            }
            const unsigned pk01 = cvt_pk_bf16(hn[0], hn[1]);
            const unsigned pk23 = cvt_pk_bf16(hn[2], hn[3]);
            // h_1 -> shb[1] (swizzled)
            *(short*)(shbb + BUFB + wb[0] + mt * 4096)       = (short)pk01;
            *(short*)(shbb + BUFB + wb[1] + mt * 4096 + 256) = (short)(pk01 >> 16);
            *(short*)(shbb + BUFB + wb[2] + mt * 4096 + 512) = (short)pk23;
            *(short*)(shbb + BUFB + wb[3] + mt * 4096 + 768) = (short)(pk23 >> 16);
        }
    }

    // ---- folded steady-state weights (pre-scaled in ws) ----
    bf16x8 Brs[4], Bzs[4], Bni[4];
    float  b_rs, b_zs, b_ni;
    {
        const float* pr = ws + WS_WSTAR + (size_t)j * HH;
        const float* pz = ws + WS_WSTAR + (size_t)(HH + j) * HH;
        const float* pn = ws + WS_WSTAR + (size_t)(2 * HH + j) * HH;
        #pragma unroll
        for (int kt = 0; kt < 4; ++kt) {
            Brs[kt] = ldw8(pr + kt * 32 + quad * 8);
            Bzs[kt] = ldw8(pz + kt * 32 + quad * 8);
            Bni[kt] = ldw8(pn + kt * 32 + quad * 8);
        }
        b_rs = ws[WS_BSTAR + j];
        b_zs = ws[WS_BSTAR + HH + j];
        b_ni = ws[WS_BSTAR + 2 * HH + j];
    }

    __syncthreads();   // step-0 h' visible to all waves

    // ================= steps: {phase2(s) || phase1(s+1)}, 1 barrier/step ===
    // body(s, qb): h_{s+1} lives in shb[qb]. Y(s) reads shb[qb]; G(s+1)
    // reads shb[qb], writes shb[qb^1]; LDS barrier. qb passed as literal.
    auto body = [&](int s, int qb, bool last) {
        (void)s;
        const int rdoff = qb * BUFB;
        // ---- phase 2: y_s = h_{s+1} @ Wout^T + bout ----
        {
            f32x4 yo = (f32x4){b_o, b_o, b_o, b_o};
            #pragma unroll
            for (int kt = 0; kt < 4; ++kt) {
                bf16x8 A2 = *(const bf16x8*)(shbb + rdoff + rb[kt] + rowtile * 4096);
                yo = MFMA(A2, Bo[kt], yo);
            }
            yp0[0]         = yo[0];
            yp0[NSTEP*II]  = yo[1];
            yp1[0]         = yo[2];
            yp1[NSTEP*II]  = yo[3];
            yp0 += II;
            yp1 += II;
        }
        if (last) return;

        // ---- phase 1: h_{s+2} from h_{s+1} (folded, K=128) ----
        const int wroff = (qb ^ 1) * BUFB;
        #pragma unroll
        for (int mt = 0; mt < 4; ++mt) {
            f32x4 ar  = (f32x4){b_rs, b_rs, b_rs, b_rs};
            f32x4 az  = (f32x4){b_zs, b_zs, b_zs, b_zs};
            f32x4 anh = (f32x4){b_nh, b_nh, b_nh, b_nh};
            f32x4 ani = (f32x4){b_ni, b_ni, b_ni, b_ni};
            #pragma unroll
            for (int kt = 0; kt < 4; ++kt) {       // 4 indep acc chains
                bf16x8 A = *(const bf16x8*)(shbb + rdoff + rb[kt] + mt * 4096);
                ar  = MFMA(A, Brs[kt], ar);
                az  = MFMA(A, Bzs[kt], az);
                anh = MFMA(A, Bnh[kt], anh);
                ani = MFMA(A, Bni[kt], ani);
            }
            float hn[4];
            #pragma unroll
            for (int reg = 0; reg < 4; ++reg) {
                const float r = sigm2(ar[reg]);
                const float z = sigm2(az[reg]);
                const float n = tanh2(ani[reg] + r * anh[reg]);
                const float hnew = n + z * (hst[mt][reg] - n);
                hst[mt][reg] = hnew;
                hn[reg] = hnew;
            }
            const unsigned pk01 = cvt_pk_bf16(hn[0], hn[1]);
            const unsigned pk23 = cvt_pk_bf16(hn[2], hn[3]);
            *(short*)(shbb + wroff + wb[0] + mt * 4096)       = (short)pk01;
            *(short*)(shbb + wroff + wb[1] + mt * 4096 + 256) = (short)(pk01 >> 16);
            *(short*)(shbb + wroff + wb[2] + mt * 4096 + 512) = (short)pk23;
            *(short*)(shbb + wroff + wb[3] + mt * 4096 + 768) = (short)(pk23 >> 16);
        }
        LDS_BARRIER();
    };

    for (int s2 = 0; s2 < NSTEP - 2; s2 += 2) {   // s = 0..27
        body(s2,     1, false);
        body(s2 + 1, 0, false);
    }
    body(NSTEP - 2, 1, false);   // s = 28
    body(NSTEP - 1, 0, true);    // s = 29: final Y only
}

extern "C" void kernel_launch(void* const* d_in, const int* in_sizes, int n_in,
                              void* d_out, int out_size, void* d_ws, size_t ws_size,
                              hipStream_t stream) {
    (void)in_sizes; (void)n_in; (void)out_size; (void)ws_size;
    const float* x    = (const float*)d_in[0];
    const float* h0   = (const float*)d_in[1];
    const float* Wih  = (const float*)d_in[2];
    const float* Whh  = (const float*)d_in[3];
    const float* bih  = (const float*)d_in[4];
    const float* bhh  = (const float*)d_in[5];
    const float* Wout = (const float*)d_in[6];
    const float* bout = (const float*)d_in[7];
    float* out = (float*)d_out;
    float* ws  = (float*)d_ws;

    fold_kernel<<<dim3(384), dim3(128), 0, stream>>>(Wih, Whh, bih, bhh,
                                                     Wout, bout, ws);
    dim3 grid(NB / BM);   // 256 blocks -> 1 per CU (8 waves = 2 waves/SIMD)
    dim3 block(512);
    gru_mfma_kernel<<<grid, block, 0, stream>>>(x, h0, Wih, Whh, bih, bhh,
                                                Wout, bout, ws, out);
}